// Round 2
// baseline (861.262 us; speedup 1.0000x reference)
//
#include <hip/hip_runtime.h>
#include <math.h>

// VanillaRNN: B=1024, T=512, I=64, H=128, O=10, fp32.
// One block per batch element. 256 threads = 4 waves.
// Wave w owns outputs j in [32w, 32w+32); lane pairs (l, l+32) split the
// 192-long dot product in half (96 MACs each), recombined with shfl_xor(32).
// Weights in VGPRs (96/thread, kept resident via launch_bounds cap=170);
// operand vector [h | x_t] in ping-pong LDS buffers -> ONE barrier per step.

#define T_STEPS 512
#define I_DIM   64
#define H_DIM   128
#define O_DIM   10
#define KTOT    192   // H + I
#define WPT     96    // K-slice per thread

__global__ __launch_bounds__(256, 3) void rnn_fused_kernel(
    const float* __restrict__ x,      // [B, T, I]
    const float* __restrict__ W_hx,   // [H, I]
    const float* __restrict__ W_hh,   // [H, H]
    const float* __restrict__ b_hh,   // [H]
    const float* __restrict__ W_ph,   // [O, H]
    const float* __restrict__ b_ph,   // [O]
    float* __restrict__ out)          // [B, O]
{
    const int b    = blockIdx.x;
    const int tid  = threadIdx.x;
    const int wave = tid >> 6;            // 0..3
    const int lane = tid & 63;
    const int half = lane >> 5;           // 0/1 within the wave
    const int j    = (wave << 5) | (lane & 31);   // 0..127

    __shared__ float v[2][KTOT];          // ping-pong: [0:128)=h, [128:192)=x_t

    // --- Preload this thread's 96-float slice of row j of [W_hh | W_hx] ---
    float w[WPT];
    if (half == 0) {
        #pragma unroll
        for (int m = 0; m < WPT; ++m) w[m] = W_hh[j * H_DIM + m];
    } else {
        #pragma unroll
        for (int m = 0; m < 32; ++m)  w[m] = W_hh[j * H_DIM + WPT + m];
        #pragma unroll
        for (int m = 0; m < I_DIM; ++m) w[32 + m] = W_hx[j * I_DIM + m];
    }
    const float bias = b_hh[j];

    const float* xb = x + (size_t)b * T_STEPS * I_DIM;

    // h0 = 0; stage x_0 into buffer 0.
    if (tid < H_DIM) v[0][tid] = 0.0f;
    if (tid < I_DIM) v[0][H_DIM + tid] = xb[tid];
    __syncthreads();

    for (int t = 0; t < T_STEPS; ++t) {
        const int p = t & 1;

        // Prefetch x_{t+1} (overlaps with the dot-product below).
        float xreg = 0.0f;
        const int tn = (t < T_STEPS - 1) ? (t + 1) : (T_STEPS - 1);
        if (tid < I_DIM) xreg = xb[tn * I_DIM + tid];

        // 96-MAC partial dot; operands via LDS (2-distinct-address broadcast,
        // free). 4 accumulators for ILP; float4 -> ds_read_b128.
        const float4* vp4 = (const float4*)&v[p][half * WPT];
        float a0 = 0.f, a1 = 0.f, a2 = 0.f, a3 = 0.f;
        #pragma unroll
        for (int m = 0; m < WPT / 4; ++m) {
            const float4 o = vp4[m];
            a0 = fmaf(w[4*m+0], o.x, a0);
            a1 = fmaf(w[4*m+1], o.y, a1);
            a2 = fmaf(w[4*m+2], o.z, a2);
            a3 = fmaf(w[4*m+3], o.w, a3);
        }
        float acc = (a0 + a1) + (a2 + a3);

        // Combine the two K-halves in-register (lanes l <-> l+32).
        acc += __shfl_xor(acc, 32);
        const float s = acc + bias;

        // tanh(s) = 1 - 2/(e^{2s}+1), via exp2 + rcp. Saturates to +-1
        // correctly for large |s| (inf -> rcp=0; 0 -> 1-2 = -1).
        const float e = __builtin_amdgcn_exp2f(s * 2.885390081777926825f); // 2*log2(e)
        const float r = __builtin_amdgcn_rcpf(e + 1.0f);
        const float hnew = fmaf(-2.0f, r, 1.0f);

        // Write next-step state into the other buffer (no WAR on v[p]).
        if (half == 0) v[1 - p][j] = hnew;            // lanes 0..31 of each wave
        if (tid < I_DIM) v[1 - p][H_DIM + tid] = xreg;
        __syncthreads();                               // one barrier per step
    }

    // After t=511 (p=1), final h sits in v[0][0:128).
    if (tid < O_DIM) {
        float acc = b_ph[tid];
        #pragma unroll 4
        for (int k = 0; k < H_DIM; ++k) acc = fmaf(W_ph[tid * H_DIM + k], v[0][k], acc);
        out[b * O_DIM + tid] = acc;
    }
}

extern "C" void kernel_launch(void* const* d_in, const int* in_sizes, int n_in,
                              void* d_out, int out_size, void* d_ws, size_t ws_size,
                              hipStream_t stream) {
    const float* x    = (const float*)d_in[0];
    const float* W_hx = (const float*)d_in[1];
    const float* W_hh = (const float*)d_in[2];
    const float* b_hh = (const float*)d_in[3];
    const float* W_ph = (const float*)d_in[4];
    const float* b_ph = (const float*)d_in[5];
    float* out = (float*)d_out;

    const int B = 1024;
    rnn_fused_kernel<<<B, 256, 0, stream>>>(x, W_hx, W_hh, b_hh, W_ph, b_ph, out);
}

// Round 3
// 768.376 us; speedup vs baseline: 1.1209x; 1.1209x over previous
//
#include <hip/hip_runtime.h>
#include <math.h>

// VanillaRNN: B=1024, T=512, I=64, H=128, O=10, fp32.
// One block per batch element. 512 threads = 8 waves.
// Output j = wave*16 + (lane&15); K-slice q = lane>>4 (4 slices x 48).
// All 4 slices of j live in ONE wave -> combine with shfl_xor(16)+shfl_xor(32).
// WPT=48 keeps per-thread regs ~70 => compiler keeps weights resident
// (rounds 1-2 failed because 96-float arrays got rematerialized/spilled).
// Operand vector [h | x_t] in ping-pong LDS buffers -> ONE barrier per step.

#define T_STEPS 512
#define I_DIM   64
#define H_DIM   128
#define O_DIM   10
#define KTOT    192   // H + I
#define WPT     48    // K-slice per thread
#define NTHR    512

__global__ __launch_bounds__(NTHR)
__attribute__((amdgpu_waves_per_eu(1, 4)))
void rnn_fused_kernel(
    const float* __restrict__ x,      // [B, T, I]
    const float* __restrict__ W_hx,   // [H, I]
    const float* __restrict__ W_hh,   // [H, H]
    const float* __restrict__ b_hh,   // [H]
    const float* __restrict__ W_ph,   // [O, H]
    const float* __restrict__ b_ph,   // [O]
    float* __restrict__ out)          // [B, O]
{
    const int b    = blockIdx.x;
    const int tid  = threadIdx.x;
    const int wave = tid >> 6;                    // 0..7
    const int lane = tid & 63;
    const int q    = lane >> 4;                   // K-slice 0..3
    const int j    = (wave << 4) | (lane & 15);   // output row 0..127

    __shared__ float v[2][KTOT];                  // ping-pong: [0:128)=h, [128:192)=x_t

    // --- Preload this thread's 48-float slice of row j of [W_hh | W_hx] ---
    float w[WPT];
    #pragma unroll
    for (int m = 0; m < WPT; ++m) {
        const int k = q * WPT + m;
        w[m] = (k < H_DIM) ? W_hh[j * H_DIM + k]
                           : W_hx[j * I_DIM + (k - H_DIM)];
    }
    const float bias = b_hh[j];

    const float* xb = x + (size_t)b * T_STEPS * I_DIM;

    // h0 = 0; stage x_0 into buffer 0.
    if (tid < H_DIM) v[0][tid] = 0.0f;
    if (tid < I_DIM) v[0][H_DIM + tid] = xb[tid];
    __syncthreads();

    for (int t = 0; t < T_STEPS; ++t) {
        const int p = t & 1;

        // Prefetch x_{t+1} (overlaps the dot-product below).
        float xreg = 0.0f;
        const int tn = (t < T_STEPS - 1) ? (t + 1) : (T_STEPS - 1);
        if (tid < I_DIM) xreg = xb[tn * I_DIM + tid];

        // 48-MAC partial dot; operands via LDS broadcast (4 distinct addrs).
        const float4* vp4 = (const float4*)&v[p][q * WPT];
        float a0 = 0.f, a1 = 0.f, a2 = 0.f, a3 = 0.f;
        #pragma unroll
        for (int m = 0; m < WPT / 4; ++m) {
            const float4 o = vp4[m];
            a0 = fmaf(w[4*m+0], o.x, a0);
            a1 = fmaf(w[4*m+1], o.y, a1);
            a2 = fmaf(w[4*m+2], o.z, a2);
            a3 = fmaf(w[4*m+3], o.w, a3);
        }
        float acc = (a0 + a1) + (a2 + a3);

        // Combine the 4 K-slices (lane bits 4 and 5 index q).
        acc += __shfl_xor(acc, 16);
        acc += __shfl_xor(acc, 32);
        const float s = acc + bias;

        // tanh(s) = 1 - 2/(e^{2s}+1) via exp2 + rcp; saturates correctly.
        const float e = __builtin_amdgcn_exp2f(s * 2.885390081777926825f); // 2*log2(e)
        const float r = __builtin_amdgcn_rcpf(e + 1.0f);
        const float hnew = fmaf(-2.0f, r, 1.0f);

        // Write next-step state into the other buffer (no WAR on v[p]).
        if (q == 0) v[1 - p][j] = hnew;                 // lanes 0..15 per wave
        if (tid < I_DIM) v[1 - p][H_DIM + tid] = xreg;
        __syncthreads();                                 // one barrier per step
    }

    // After t=511 (p=1), final h sits in v[0][0:128).
    if (tid < O_DIM) {
        float acc = b_ph[tid];
        #pragma unroll 4
        for (int k = 0; k < H_DIM; ++k) acc = fmaf(W_ph[tid * H_DIM + k], v[0][k], acc);
        out[b * O_DIM + tid] = acc;
    }
}

extern "C" void kernel_launch(void* const* d_in, const int* in_sizes, int n_in,
                              void* d_out, int out_size, void* d_ws, size_t ws_size,
                              hipStream_t stream) {
    const float* x    = (const float*)d_in[0];
    const float* W_hx = (const float*)d_in[1];
    const float* W_hh = (const float*)d_in[2];
    const float* b_hh = (const float*)d_in[3];
    const float* W_ph = (const float*)d_in[4];
    const float* b_ph = (const float*)d_in[5];
    float* out = (float*)d_out;

    const int B = 1024;
    rnn_fused_kernel<<<B, NTHR, 0, stream>>>(x, W_hx, W_hh, b_hh, W_ph, b_ph, out);
}